// Round 1
// baseline (173.928 us; speedup 1.0000x reference)
//
#include <hip/hip_runtime.h>
#include <stdint.h>
#include <stddef.h>

#define NB 2
#define NN 8000
#define NC 64
#define NKT 500         // N/16 key tiles
#define STAGE_KT 20     // key tiles staged per LDS buffer
#define NSTAGE 25       // 500/20
#define RESCALE_THR 8.0f

#define KV_BYTES ((size_t)NB * NKT * 5 * 64 * 8)   // 2,560,000 B: f frag + 4 h frags, bf16
#define GB_OFF   KV_BYTES                          // g frags: 512,000 B

typedef float f32x4 __attribute__((ext_vector_type(4)));
typedef short s16x4 __attribute__((ext_vector_type(4)));

__device__ inline short f2bf(float f) {
    union { float f; uint32_t u; } v; v.f = f;
    uint32_t u = v.u + 0x7FFFu + ((v.u >> 16) & 1u);   // RNE to bf16
    return (short)(u >> 16);
}

// ---------------------------------------------------------------------------
// Kernel 1: projections f = xWf, g = xWg, h = xWh, written to ws in MFMA
// fragment order (bf16).
//   kv[b][kt][sub][lane] (uint2 = 4 bf16), sub0 = f A-frag (K-dim padded 8->16
//   with zeros), sub1..4 = h B-frags for column blocks cb=0..3.
//   gB[b][qt][lane]     = g B-frag (padded like f).
// Fragment maps (v_mfma_f32_16x16x16_bf16):
//   A: row = lane&15, k = (lane>>4)*4 + e
//   B: col = lane&15, k = (lane>>4)*4 + e
//   C/D: col = lane&15, row = (lane>>4)*4 + reg
// ---------------------------------------------------------------------------
__global__ __launch_bounds__(256) void proj_kernel(
    const float* __restrict__ x,
    const float* __restrict__ Wf,
    const float* __restrict__ Wg,
    const float* __restrict__ Wh,
    uint8_t* __restrict__ ws)
{
    __shared__ float Wh_s[64][68];
    __shared__ float Wf_s[64][8];
    __shared__ float Wg_s[64][8];
    __shared__ float x_s[4][16][68];
    __shared__ float h_s[4][16][68];

    const int tid = threadIdx.x;
    const int L = tid & 63, w = tid >> 6;
    const int lane16 = L & 15, g4 = L >> 4;

    for (int i = tid; i < 64 * 64; i += 256) Wh_s[i >> 6][i & 63] = Wh[i];
    for (int i = tid; i < 64 * 8; i += 256) {
        Wf_s[i >> 3][i & 7] = Wf[i];
        Wg_s[i >> 3][i & 7] = Wg[i];
    }

    const int ktg = blockIdx.x * 4 + w;      // 0..999
    const int b = ktg / NKT, ktb = ktg % NKT;
    const float* xsrc = x + ((size_t)b * NN + (size_t)ktb * 16) * NC;

    #pragma unroll
    for (int i = 0; i < 4; i++) {            // 16 rows x 64 cols, coalesced
        int F = i * 256 + L * 4;
        f32x4 v = *(const f32x4*)(xsrc + F);
        *(f32x4*)&x_s[w][F >> 6][F & 63] = v;
    }
    __syncthreads();

    uint2* kv = (uint2*)ws;
    uint2* gB = (uint2*)(ws + GB_OFF);

    // ---- f and g fragments (each lane: row = lane16, d = 4*(g4&1)+e) ----
    {
        float fa0 = 0, fa1 = 0, fa2 = 0, fa3 = 0;
        float ga0 = 0, ga1 = 0, ga2 = 0, ga3 = 0;
        const int d0 = (g4 & 1) * 4;
        #pragma unroll 4
        for (int k = 0; k < 64; k++) {
            float xv = x_s[w][lane16][k];
            fa0 += xv * Wf_s[k][d0 + 0]; fa1 += xv * Wf_s[k][d0 + 1];
            fa2 += xv * Wf_s[k][d0 + 2]; fa3 += xv * Wf_s[k][d0 + 3];
            ga0 += xv * Wg_s[k][d0 + 0]; ga1 += xv * Wg_s[k][d0 + 1];
            ga2 += xv * Wg_s[k][d0 + 2]; ga3 += xv * Wg_s[k][d0 + 3];
        }
        const bool valid = (g4 < 2);         // k-dim 8..15 is zero padding
        union { s16x4 v; uint2 u; } fp, gp;
        fp.v[0] = valid ? f2bf(fa0) : (short)0;
        fp.v[1] = valid ? f2bf(fa1) : (short)0;
        fp.v[2] = valid ? f2bf(fa2) : (short)0;
        fp.v[3] = valid ? f2bf(fa3) : (short)0;
        gp.v[0] = valid ? f2bf(ga0) : (short)0;
        gp.v[1] = valid ? f2bf(ga1) : (short)0;
        gp.v[2] = valid ? f2bf(ga2) : (short)0;
        gp.v[3] = valid ? f2bf(ga3) : (short)0;
        kv[((size_t)(b * NKT + ktb) * 5 + 0) * 64 + L] = fp.u;
        gB[(size_t)(b * NKT + ktb) * 64 + L] = gp.u;
    }

    // ---- h: each lane computes row = lane16, cols c0..c0+15 ----
    {
        float ha[16];
        #pragma unroll
        for (int i = 0; i < 16; i++) ha[i] = 0.f;
        const int c0 = g4 * 16;
        for (int k = 0; k < 64; k++) {
            float xv = x_s[w][lane16][k];
            const f32x4 w0 = *(const f32x4*)&Wh_s[k][c0 + 0];
            const f32x4 w1 = *(const f32x4*)&Wh_s[k][c0 + 4];
            const f32x4 w2 = *(const f32x4*)&Wh_s[k][c0 + 8];
            const f32x4 w3 = *(const f32x4*)&Wh_s[k][c0 + 12];
            #pragma unroll
            for (int e = 0; e < 4; e++) {
                ha[e]      += xv * w0[e];
                ha[4 + e]  += xv * w1[e];
                ha[8 + e]  += xv * w2[e];
                ha[12 + e] += xv * w3[e];
            }
        }
        #pragma unroll
        for (int i = 0; i < 4; i++) {
            f32x4 t; t[0] = ha[4*i]; t[1] = ha[4*i+1]; t[2] = ha[4*i+2]; t[3] = ha[4*i+3];
            *(f32x4*)&h_s[w][lane16][c0 + 4 * i] = t;
        }
    }
    __syncthreads();

    // ---- h B-fragments: lane needs h[key=(g4*4+e)][cb*16+lane16] ----
    #pragma unroll
    for (int cb = 0; cb < 4; cb++) {
        union { s16x4 v; uint2 u; } hp;
        #pragma unroll
        for (int e = 0; e < 4; e++)
            hp.v[e] = f2bf(h_s[w][g4 * 4 + e][cb * 16 + lane16]);
        kv[((size_t)(b * NKT + ktb) * 5 + 1 + cb) * 64 + L] = hp.u;
    }
}

// ---------------------------------------------------------------------------
// Kernel 2: flash attention. 4 waves/block, wave owns 16 queries.
// Swapped QK^T: S = mfma(A=f, B=g) -> lane holds S for (q = lane&15,
// keys = (lane>>4)*4+reg), which IS the PV A-fragment layout. No cross-lane
// data movement for P. Online softmax with defer-max (THR=8).
// ---------------------------------------------------------------------------
__global__ __launch_bounds__(256) void attn_kernel(
    const float* __restrict__ x,
    const float* __restrict__ gammap,
    const uint8_t* __restrict__ ws,
    float* __restrict__ out)
{
    __shared__ uint2 kvs[STAGE_KT * 5 * 64];   // 51,200 B

    const int tid = threadIdx.x;
    const int L = tid & 63, w = tid >> 6;
    const int lane16 = L & 15, g4 = L >> 4;
    const int b = blockIdx.x / (NN / 64);
    const int qblk = blockIdx.x % (NN / 64);
    const int qt = qblk * 4 + w;               // 16-query tile index

    const uint2* kv = (const uint2*)ws;
    const uint2* gB = (const uint2*)(ws + GB_OFF);

    s16x4 bg;
    { union { uint2 u; s16x4 v; } t; t.u = gB[(size_t)(b * NKT + qt) * 64 + L]; bg = t.v; }

    float m_run = -1e30f, l_part = 0.f;
    f32x4 o0 = {0, 0, 0, 0}, o1 = {0, 0, 0, 0}, o2 = {0, 0, 0, 0}, o3 = {0, 0, 0, 0};

    for (int st = 0; st < NSTAGE; st++) {
        __syncthreads();                        // protect LDS reuse
        const uint2* src = kv + (size_t)(b * NKT + st * STAGE_KT) * 5 * 64;
        uint2 tmp[25];
        #pragma unroll
        for (int i = 0; i < 25; i++) tmp[i] = src[tid + i * 256];
        #pragma unroll
        for (int i = 0; i < 25; i++) kvs[tid + i * 256] = tmp[i];
        __syncthreads();

        for (int ktl = 0; ktl < STAGE_KT; ktl++) {
            const uint2* base = &kvs[ktl * 5 * 64];
            s16x4 af;
            { union { uint2 u; s16x4 v; } t; t.u = base[L]; af = t.v; }
            f32x4 z = {0, 0, 0, 0};
            f32x4 s = __builtin_amdgcn_mfma_f32_16x16x16bf16_1k(af, bg, z, 0, 0, 0);

            // per-query tile max (reduce over reg, then over 4 lane groups)
            float mt = fmaxf(fmaxf(s[0], s[1]), fmaxf(s[2], s[3]));
            mt = fmaxf(mt, __shfl_xor(mt, 16));
            mt = fmaxf(mt, __shfl_xor(mt, 32));

            if (__any(mt > m_run + RESCALE_THR)) {
                float mnew = fmaxf(m_run, mt);
                float sc = __expf(m_run - mnew);
                l_part *= sc;
                // O rows are q = g4*4+r -> scale lives at lane (g4*4+r)
                float s0 = __shfl(sc, g4 * 4 + 0);
                float s1 = __shfl(sc, g4 * 4 + 1);
                float s2 = __shfl(sc, g4 * 4 + 2);
                float s3 = __shfl(sc, g4 * 4 + 3);
                o0[0] *= s0; o0[1] *= s1; o0[2] *= s2; o0[3] *= s3;
                o1[0] *= s0; o1[1] *= s1; o1[2] *= s2; o1[3] *= s3;
                o2[0] *= s0; o2[1] *= s1; o2[2] *= s2; o2[3] *= s3;
                o3[0] *= s0; o3[1] *= s1; o3[2] *= s2; o3[3] *= s3;
                m_run = mnew;
            }

            float p0 = __expf(s[0] - m_run);
            float p1 = __expf(s[1] - m_run);
            float p2 = __expf(s[2] - m_run);
            float p3 = __expf(s[3] - m_run);
            l_part += (p0 + p1) + (p2 + p3);

            union { s16x4 v; uint2 u; } pp;
            pp.v[0] = f2bf(p0); pp.v[1] = f2bf(p1);
            pp.v[2] = f2bf(p2); pp.v[3] = f2bf(p3);

            s16x4 h0, h1, h2, h3;
            { union { uint2 u; s16x4 v; } t; t.u = base[ 64 + L]; h0 = t.v; }
            { union { uint2 u; s16x4 v; } t; t.u = base[128 + L]; h1 = t.v; }
            { union { uint2 u; s16x4 v; } t; t.u = base[192 + L]; h2 = t.v; }
            { union { uint2 u; s16x4 v; } t; t.u = base[256 + L]; h3 = t.v; }

            o0 = __builtin_amdgcn_mfma_f32_16x16x16bf16_1k(pp.v, h0, o0, 0, 0, 0);
            o1 = __builtin_amdgcn_mfma_f32_16x16x16bf16_1k(pp.v, h1, o1, 0, 0, 0);
            o2 = __builtin_amdgcn_mfma_f32_16x16x16bf16_1k(pp.v, h2, o2, 0, 0, 0);
            o3 = __builtin_amdgcn_mfma_f32_16x16x16bf16_1k(pp.v, h3, o3, 0, 0, 0);
        }
    }

    // ---- epilogue: finish l, normalize, residual + gamma, store ----
    float lsum = l_part;
    lsum += __shfl_xor(lsum, 16);
    lsum += __shfl_xor(lsum, 32);
    float linv = 1.f / lsum;                   // for q = lane16
    float li0 = __shfl(linv, g4 * 4 + 0);
    float li1 = __shfl(linv, g4 * 4 + 1);
    float li2 = __shfl(linv, g4 * 4 + 2);
    float li3 = __shfl(linv, g4 * 4 + 3);
    const float gam = gammap[0];
    const int q0 = qt * 16 + g4 * 4;           // global row of reg 0

    #pragma unroll
    for (int r = 0; r < 4; r++) {
        float lr = (r == 0) ? li0 : (r == 1) ? li1 : (r == 2) ? li2 : li3;
        size_t rowoff = ((size_t)b * NN + q0 + r) * NC;
        float ov0 = o0[r], ov1 = o1[r], ov2 = o2[r], ov3 = o3[r];
        out[rowoff +  0 + lane16] = gam * (ov0 * lr) + x[rowoff +  0 + lane16];
        out[rowoff + 16 + lane16] = gam * (ov1 * lr) + x[rowoff + 16 + lane16];
        out[rowoff + 32 + lane16] = gam * (ov2 * lr) + x[rowoff + 32 + lane16];
        out[rowoff + 48 + lane16] = gam * (ov3 * lr) + x[rowoff + 48 + lane16];
    }
}

extern "C" void kernel_launch(void* const* d_in, const int* in_sizes, int n_in,
                              void* d_out, int out_size, void* d_ws, size_t ws_size,
                              hipStream_t stream) {
    const float* x     = (const float*)d_in[0];
    const float* Wf    = (const float*)d_in[1];
    const float* Wg    = (const float*)d_in[2];
    const float* Wh    = (const float*)d_in[3];
    const float* gamma = (const float*)d_in[4];
    float* out = (float*)d_out;
    uint8_t* ws = (uint8_t*)d_ws;

    proj_kernel<<<250, 256, 0, stream>>>(x, Wf, Wg, Wh, ws);
    attn_kernel<<<250, 256, 0, stream>>>(x, gamma, ws, out);
}

// Round 2
// 79.962 us; speedup vs baseline: 2.1751x; 2.1751x over previous
//
#include <hip/hip_runtime.h>
#include <stdint.h>
#include <stddef.h>

#define NB 2
#define NN 8000
#define NC 64
#define NKT 500          // N/16 key tiles
#define SPLIT 5          // key-split factor (flash-decoding)
#define TILES_PER_SPLIT 100
#define STAGE_KT 10      // key tiles staged per LDS buffer
#define NSTAGE 10        // TILES_PER_SPLIT / STAGE_KT
#define RESCALE_THR 8.0f // log2 domain
#define LOG2E 1.44269504f

// ---- workspace layout (bytes) ----
#define KV_BYTES  ((size_t)NB * NKT * 5 * 64 * 8)        // 2,560,000  f + 4 h frags (bf16)
#define GB_OFF    KV_BYTES                               // g frags: 512,000
#define GB_BYTES  ((size_t)NB * NKT * 64 * 8)
#define PML_OFF   (GB_OFF + GB_BYTES)                    // m[16],l[16] per (b,qt,split)
#define PML_BYTES ((size_t)NB * NKT * SPLIT * 32 * 4)    // 640,000
#define PO_OFF    (PML_OFF + PML_BYTES)                  // O[16][64] per (b,qt,split)
#define PO_BYTES  ((size_t)NB * NKT * SPLIT * 1024 * 4)  // 20,480,000

typedef float f32x4 __attribute__((ext_vector_type(4)));
typedef short s16x4 __attribute__((ext_vector_type(4)));

__device__ inline short f2bf(float f) {
    union { float f; uint32_t u; } v; v.f = f;
    uint32_t u = v.u + 0x7FFFu + ((v.u >> 16) & 1u);   // RNE to bf16
    return (short)(u >> 16);
}
__device__ inline short f2bf_fast(float f) {           // round-to-nearest (p > 0)
    union { float f; uint32_t u; } v; v.f = f;
    return (short)((v.u + 0x8000u) >> 16);
}

// ---------------------------------------------------------------------------
// Kernel 1: projections f = x(Wf*log2e), g = xWg, h = xWh, in MFMA fragment
// order (bf16). kv[b][kt][sub][lane]: sub0 = f A-frag (K padded 8->16 zeros),
// sub1..4 = h B-frags per column block. gB[b][qt][lane] = g B-frag.
// mfma_f32_16x16x16_bf16 maps: A row=lane&15,k=(lane>>4)*4+e ; B col=lane&15,
// k=(lane>>4)*4+e ; C/D col=lane&15, row=(lane>>4)*4+reg.
// ---------------------------------------------------------------------------
__global__ __launch_bounds__(256) void proj_kernel(
    const float* __restrict__ x,
    const float* __restrict__ Wf,
    const float* __restrict__ Wg,
    const float* __restrict__ Wh,
    uint8_t* __restrict__ ws)
{
    __shared__ float Wh_s[64][68];
    __shared__ float Wf_s[64][8];
    __shared__ float Wg_s[64][8];
    __shared__ float x_s[4][16][68];
    __shared__ float h_s[4][16][68];

    const int tid = threadIdx.x;
    const int L = tid & 63, w = tid >> 6;
    const int lane16 = L & 15, g4 = L >> 4;

    for (int i = tid; i < 64 * 64; i += 256) Wh_s[i >> 6][i & 63] = Wh[i];
    for (int i = tid; i < 64 * 8; i += 256) {
        Wf_s[i >> 3][i & 7] = Wf[i] * LOG2E;   // fold log2e -> scores in log2 domain
        Wg_s[i >> 3][i & 7] = Wg[i];
    }

    const int ktg = blockIdx.x * 4 + w;      // 0..999
    const int b = ktg / NKT, ktb = ktg % NKT;
    const float* xsrc = x + ((size_t)b * NN + (size_t)ktb * 16) * NC;

    #pragma unroll
    for (int i = 0; i < 4; i++) {
        int F = i * 256 + L * 4;
        f32x4 v = *(const f32x4*)(xsrc + F);
        *(f32x4*)&x_s[w][F >> 6][F & 63] = v;
    }
    __syncthreads();

    uint2* kv = (uint2*)ws;
    uint2* gB = (uint2*)(ws + GB_OFF);

    {
        float fa0 = 0, fa1 = 0, fa2 = 0, fa3 = 0;
        float ga0 = 0, ga1 = 0, ga2 = 0, ga3 = 0;
        const int d0 = (g4 & 1) * 4;
        #pragma unroll 4
        for (int k = 0; k < 64; k++) {
            float xv = x_s[w][lane16][k];
            fa0 += xv * Wf_s[k][d0 + 0]; fa1 += xv * Wf_s[k][d0 + 1];
            fa2 += xv * Wf_s[k][d0 + 2]; fa3 += xv * Wf_s[k][d0 + 3];
            ga0 += xv * Wg_s[k][d0 + 0]; ga1 += xv * Wg_s[k][d0 + 1];
            ga2 += xv * Wg_s[k][d0 + 2]; ga3 += xv * Wg_s[k][d0 + 3];
        }
        const bool valid = (g4 < 2);
        union { s16x4 v; uint2 u; } fp, gp;
        fp.v[0] = valid ? f2bf(fa0) : (short)0;
        fp.v[1] = valid ? f2bf(fa1) : (short)0;
        fp.v[2] = valid ? f2bf(fa2) : (short)0;
        fp.v[3] = valid ? f2bf(fa3) : (short)0;
        gp.v[0] = valid ? f2bf(ga0) : (short)0;
        gp.v[1] = valid ? f2bf(ga1) : (short)0;
        gp.v[2] = valid ? f2bf(ga2) : (short)0;
        gp.v[3] = valid ? f2bf(ga3) : (short)0;
        kv[((size_t)(b * NKT + ktb) * 5 + 0) * 64 + L] = fp.u;
        gB[(size_t)(b * NKT + ktb) * 64 + L] = gp.u;
    }

    {
        float ha[16];
        #pragma unroll
        for (int i = 0; i < 16; i++) ha[i] = 0.f;
        const int c0 = g4 * 16;
        for (int k = 0; k < 64; k++) {
            float xv = x_s[w][lane16][k];
            const f32x4 w0 = *(const f32x4*)&Wh_s[k][c0 + 0];
            const f32x4 w1 = *(const f32x4*)&Wh_s[k][c0 + 4];
            const f32x4 w2 = *(const f32x4*)&Wh_s[k][c0 + 8];
            const f32x4 w3 = *(const f32x4*)&Wh_s[k][c0 + 12];
            #pragma unroll
            for (int e = 0; e < 4; e++) {
                ha[e]      += xv * w0[e];
                ha[4 + e]  += xv * w1[e];
                ha[8 + e]  += xv * w2[e];
                ha[12 + e] += xv * w3[e];
            }
        }
        #pragma unroll
        for (int i = 0; i < 4; i++) {
            f32x4 t; t[0] = ha[4*i]; t[1] = ha[4*i+1]; t[2] = ha[4*i+2]; t[3] = ha[4*i+3];
            *(f32x4*)&h_s[w][lane16][c0 + 4 * i] = t;
        }
    }
    __syncthreads();

    #pragma unroll
    for (int cb = 0; cb < 4; cb++) {
        union { s16x4 v; uint2 u; } hp;
        #pragma unroll
        for (int e = 0; e < 4; e++)
            hp.v[e] = f2bf(h_s[w][g4 * 4 + e][cb * 16 + lane16]);
        kv[((size_t)(b * NKT + ktb) * 5 + 1 + cb) * 64 + L] = hp.u;
    }
}

// ---------------------------------------------------------------------------
// Kernel 2: flash attention, key-split. Block = (b, qblk of 4 qtiles, split).
// 4 waves share LDS-staged keys for the split's 100 tiles; each wave owns one
// 16-query tile. Writes partial (m, l, O) per (b,qt,split) to workspace.
// ---------------------------------------------------------------------------
__global__ __launch_bounds__(256, 6) void attn_kernel(
    const uint8_t* __restrict__ ws_in,
    uint8_t* __restrict__ ws_out)
{
    __shared__ uint2 kvs[STAGE_KT * 5 * 64];   // 25,600 B

    const int tid = threadIdx.x;
    const int L = tid & 63, w = tid >> 6;
    const int lane16 = L & 15, g4 = L >> 4;

    const int bid = blockIdx.x;                // 1250 blocks
    const int qblk = bid % 125;
    const int bs = bid / 125;                  // 0..9
    const int b = bs / SPLIT, s = bs % SPLIT;
    const int qt = qblk * 4 + w;

    const uint2* kv = (const uint2*)ws_in;
    const uint2* gB = (const uint2*)(ws_in + GB_OFF);
    float* part_ml = (float*)(ws_out + PML_OFF);
    float* part_O  = (float*)(ws_out + PO_OFF);

    s16x4 bg;
    { union { uint2 u; s16x4 v; } t; t.u = gB[(size_t)(b * NKT + qt) * 64 + L]; bg = t.v; }

    float m_run = -1e30f, l_part = 0.f;
    f32x4 o0 = {0, 0, 0, 0}, o1 = {0, 0, 0, 0}, o2 = {0, 0, 0, 0}, o3 = {0, 0, 0, 0};

    const int kt0 = s * TILES_PER_SPLIT;

    for (int st = 0; st < NSTAGE; st++) {
        __syncthreads();
        const uint2* src = kv + (size_t)(b * NKT + kt0 + st * STAGE_KT) * 5 * 64;
        {
            uint2 tmp[12];
            #pragma unroll
            for (int i = 0; i < 12; i++) tmp[i] = src[tid + i * 256];
            uint2 tail;
            if (tid < 128) tail = src[3072 + tid];
            #pragma unroll
            for (int i = 0; i < 12; i++) kvs[tid + i * 256] = tmp[i];
            if (tid < 128) kvs[3072 + tid] = tail;
        }
        __syncthreads();

        for (int ktl = 0; ktl < STAGE_KT; ktl++) {
            const uint2* base = &kvs[ktl * 5 * 64];
            s16x4 af;
            { union { uint2 u; s16x4 v; } t; t.u = base[L]; af = t.v; }
            f32x4 z = {0, 0, 0, 0};
            f32x4 sv = __builtin_amdgcn_mfma_f32_16x16x16bf16_1k(af, bg, z, 0, 0, 0);

            // per-lane max over 4 regs; cross-lane only when rescale triggers
            float mt = fmaxf(fmaxf(sv[0], sv[1]), fmaxf(sv[2], sv[3]));
            if (__any(mt > m_run + RESCALE_THR)) {
                float mc = fmaxf(mt, __shfl_xor(mt, 16));
                mc = fmaxf(mc, __shfl_xor(mc, 32));
                float mnew = fmaxf(m_run, mc);
                float sc = exp2f(m_run - mnew);
                l_part *= sc;
                float s0 = __shfl(sc, g4 * 4 + 0);
                float s1 = __shfl(sc, g4 * 4 + 1);
                float s2 = __shfl(sc, g4 * 4 + 2);
                float s3 = __shfl(sc, g4 * 4 + 3);
                o0[0] *= s0; o0[1] *= s1; o0[2] *= s2; o0[3] *= s3;
                o1[0] *= s0; o1[1] *= s1; o1[2] *= s2; o1[3] *= s3;
                o2[0] *= s0; o2[1] *= s1; o2[2] *= s2; o2[3] *= s3;
                o3[0] *= s0; o3[1] *= s1; o3[2] *= s2; o3[3] *= s3;
                m_run = mnew;
            }

            float p0 = exp2f(sv[0] - m_run);
            float p1 = exp2f(sv[1] - m_run);
            float p2 = exp2f(sv[2] - m_run);
            float p3 = exp2f(sv[3] - m_run);
            l_part += (p0 + p1) + (p2 + p3);

            union { s16x4 v; uint2 u; } pp;
            pp.v[0] = f2bf_fast(p0); pp.v[1] = f2bf_fast(p1);
            pp.v[2] = f2bf_fast(p2); pp.v[3] = f2bf_fast(p3);

            s16x4 h0, h1, h2, h3;
            { union { uint2 u; s16x4 v; } t; t.u = base[ 64 + L]; h0 = t.v; }
            { union { uint2 u; s16x4 v; } t; t.u = base[128 + L]; h1 = t.v; }
            { union { uint2 u; s16x4 v; } t; t.u = base[192 + L]; h2 = t.v; }
            { union { uint2 u; s16x4 v; } t; t.u = base[256 + L]; h3 = t.v; }

            o0 = __builtin_amdgcn_mfma_f32_16x16x16bf16_1k(pp.v, h0, o0, 0, 0, 0);
            o1 = __builtin_amdgcn_mfma_f32_16x16x16bf16_1k(pp.v, h1, o1, 0, 0, 0);
            o2 = __builtin_amdgcn_mfma_f32_16x16x16bf16_1k(pp.v, h2, o2, 0, 0, 0);
            o3 = __builtin_amdgcn_mfma_f32_16x16x16bf16_1k(pp.v, h3, o3, 0, 0, 0);
        }
    }

    // ---- epilogue: reduce l across lane groups, store partials ----
    float lsum = l_part;
    lsum += __shfl_xor(lsum, 16);
    lsum += __shfl_xor(lsum, 32);

    const size_t pslot = (size_t)(b * NKT + qt) * SPLIT + s;
    if (g4 == 0) {
        part_ml[pslot * 32 + lane16] = m_run;
        part_ml[pslot * 32 + 16 + lane16] = lsum;
    }
    float* obase = part_O + pslot * 1024;
    #pragma unroll
    for (int r = 0; r < 4; r++) {
        const int row = g4 * 4 + r;
        obase[row * 64 +  0 + lane16] = o0[r];
        obase[row * 64 + 16 + lane16] = o1[r];
        obase[row * 64 + 32 + lane16] = o2[r];
        obase[row * 64 + 48 + lane16] = o3[r];
    }
}

// ---------------------------------------------------------------------------
// Kernel 3: combine splits + gamma/residual. One thread per output element.
// ---------------------------------------------------------------------------
__global__ __launch_bounds__(256) void combine_kernel(
    const float* __restrict__ x,
    const float* __restrict__ gammap,
    const uint8_t* __restrict__ ws,
    float* __restrict__ out)
{
    const int idx = blockIdx.x * 256 + threadIdx.x;   // 0 .. 1,023,999
    const int c = idx & 63;
    const int row_g = idx >> 6;                        // 0..15999
    const int b = row_g / NN;
    const int row = row_g - b * NN;
    const int qt = row >> 4, q = row & 15;

    const float* part_ml = (const float*)(ws + PML_OFF);
    const float* part_O  = (const float*)(ws + PO_OFF);
    const size_t pbase = (size_t)(b * NKT + qt) * SPLIT;

    float m_s[SPLIT];
    float M = -1e30f;
    #pragma unroll
    for (int s = 0; s < SPLIT; s++) {
        m_s[s] = part_ml[(pbase + s) * 32 + q];
        M = fmaxf(M, m_s[s]);
    }
    float Lsum = 0.f, O = 0.f;
    #pragma unroll
    for (int s = 0; s < SPLIT; s++) {
        float wgt = exp2f(m_s[s] - M);
        Lsum += part_ml[(pbase + s) * 32 + 16 + q] * wgt;
        O += part_O[((pbase + s) * 16 + q) * 64 + c] * wgt;
    }
    out[idx] = gammap[0] * (O / Lsum) + x[idx];
}

extern "C" void kernel_launch(void* const* d_in, const int* in_sizes, int n_in,
                              void* d_out, int out_size, void* d_ws, size_t ws_size,
                              hipStream_t stream) {
    const float* x     = (const float*)d_in[0];
    const float* Wf    = (const float*)d_in[1];
    const float* Wg    = (const float*)d_in[2];
    const float* Wh    = (const float*)d_in[3];
    const float* gamma = (const float*)d_in[4];
    float* out = (float*)d_out;
    uint8_t* ws = (uint8_t*)d_ws;

    proj_kernel<<<250, 256, 0, stream>>>(x, Wf, Wg, Wh, ws);
    attn_kernel<<<NB * 125 * SPLIT, 256, 0, stream>>>(ws, ws);
    combine_kernel<<<(NB * NN * NC) / 256, 256, 0, stream>>>(x, gamma, ws, out);
}

// Round 4
// 76.606 us; speedup vs baseline: 2.2704x; 1.0438x over previous
//
#include <hip/hip_runtime.h>
#include <stdint.h>
#include <stddef.h>

#define NB 2
#define NN 8000
#define NC 64
#define NKT 500          // N/16 key tiles
#define STAGE_KT 5       // key tiles staged per LDS buffer (12.8 KB)
#define RESCALE_THR 8.0f // log2 domain
#define LOG2E 1.44269504f

// ---- workspace layout (bytes) ----
#define KV_BYTES  ((size_t)NB * NKT * 5 * 64 * 8)   // 2,560,000: f frag + 4 h frags (bf16)
#define GB_OFF    KV_BYTES                          // g frags
#define GB_BYTES  ((size_t)NB * NKT * 64 * 8)       // 512,000
#define PML_OFF   (GB_OFF + GB_BYTES)               // m[16], l[16] per (b,qt,split)

__host__ __device__ constexpr size_t pml_bytes(int s) { return (size_t)NB * NKT * s * 32 * 4; }
__host__ __device__ constexpr size_t po_off(int s)    { return PML_OFF + pml_bytes(s); }
// partial O: per (b,qt,split) 16 rows x 16 j x uint2 (4 bf16) = 2048 B
__host__ __device__ constexpr size_t po_bytes(int s)  { return (size_t)NB * NKT * s * 2048; }

typedef float f32x4 __attribute__((ext_vector_type(4)));
typedef short s16x4 __attribute__((ext_vector_type(4)));

__device__ inline short f2bf(float f) {                // RNE to bf16 (bitwise, proven)
    union { float f; uint32_t u; } v; v.f = f;
    uint32_t u = v.u + 0x7FFFu + ((v.u >> 16) & 1u);
    return (short)(u >> 16);
}
__device__ inline short f2bf_fast(float f) {           // round-half-up in magnitude
    union { float f; uint32_t u; } v; v.f = f;
    return (short)((v.u + 0x8000u) >> 16);
}

// ---------------------------------------------------------------------------
// Kernel 1: projections f = x(Wf*log2e), g = xWg, h = xWh, in MFMA fragment
// order (bf16). kv[b][kt][sub][lane]: sub0 = f A-frag (K padded 8->16 zeros),
// sub1..4 = h B-frags per column block. gB[b][qt][lane] = g B-frag.
// mfma_f32_16x16x16_bf16 maps: A row=lane&15,k=(lane>>4)*4+e ; B col=lane&15,
// k=(lane>>4)*4+e ; C/D col=lane&15, row=(lane>>4)*4+reg.
// ---------------------------------------------------------------------------
__global__ __launch_bounds__(256) void proj_kernel(
    const float* __restrict__ x,
    const float* __restrict__ Wf,
    const float* __restrict__ Wg,
    const float* __restrict__ Wh,
    uint8_t* __restrict__ ws)
{
    __shared__ float Wh_s[64][68];
    __shared__ float Wf_s[64][8];
    __shared__ float Wg_s[64][8];
    __shared__ float x_s[4][16][68];
    __shared__ float h_s[4][16][68];

    const int tid = threadIdx.x;
    const int L = tid & 63, w = tid >> 6;
    const int lane16 = L & 15, g4 = L >> 4;

    for (int i = tid; i < 64 * 64; i += 256) Wh_s[i >> 6][i & 63] = Wh[i];
    for (int i = tid; i < 64 * 8; i += 256) {
        Wf_s[i >> 3][i & 7] = Wf[i] * LOG2E;   // scores in log2 domain
        Wg_s[i >> 3][i & 7] = Wg[i];
    }

    const int ktg = blockIdx.x * 4 + w;      // 0..999
    const int b = ktg / NKT, ktb = ktg % NKT;
    const float* xsrc = x + ((size_t)b * NN + (size_t)ktb * 16) * NC;

    #pragma unroll
    for (int i = 0; i < 4; i++) {
        int F = i * 256 + L * 4;
        f32x4 v = *(const f32x4*)(xsrc + F);
        *(f32x4*)&x_s[w][F >> 6][F & 63] = v;
    }
    __syncthreads();

    uint2* kv = (uint2*)ws;
    uint2* gB = (uint2*)(ws + GB_OFF);

    {
        float fa0 = 0, fa1 = 0, fa2 = 0, fa3 = 0;
        float ga0 = 0, ga1 = 0, ga2 = 0, ga3 = 0;
        const int d0 = (g4 & 1) * 4;
        #pragma unroll 4
        for (int k = 0; k < 64; k++) {
            float xv = x_s[w][lane16][k];
            fa0 += xv * Wf_s[k][d0 + 0]; fa1 += xv * Wf_s[k][d0 + 1];
            fa2 += xv * Wf_s[k][d0 + 2]; fa3 += xv * Wf_s[k][d0 + 3];
            ga0 += xv * Wg_s[k][d0 + 0]; ga1 += xv * Wg_s[k][d0 + 1];
            ga2 += xv * Wg_s[k][d0 + 2]; ga3 += xv * Wg_s[k][d0 + 3];
        }
        const bool valid = (g4 < 2);
        union { s16x4 v; uint2 u; } fp, gp;
        fp.v[0] = valid ? f2bf(fa0) : (short)0;
        fp.v[1] = valid ? f2bf(fa1) : (short)0;
        fp.v[2] = valid ? f2bf(fa2) : (short)0;
        fp.v[3] = valid ? f2bf(fa3) : (short)0;
        gp.v[0] = valid ? f2bf(ga0) : (short)0;
        gp.v[1] = valid ? f2bf(ga1) : (short)0;
        gp.v[2] = valid ? f2bf(ga2) : (short)0;
        gp.v[3] = valid ? f2bf(ga3) : (short)0;
        kv[((size_t)(b * NKT + ktb) * 5 + 0) * 64 + L] = fp.u;
        gB[(size_t)(b * NKT + ktb) * 64 + L] = gp.u;
    }

    {
        float ha[16];
        #pragma unroll
        for (int i = 0; i < 16; i++) ha[i] = 0.f;
        const int c0 = g4 * 16;
        for (int k = 0; k < 64; k++) {
            float xv = x_s[w][lane16][k];
            const f32x4 w0 = *(const f32x4*)&Wh_s[k][c0 + 0];
            const f32x4 w1 = *(const f32x4*)&Wh_s[k][c0 + 4];
            const f32x4 w2 = *(const f32x4*)&Wh_s[k][c0 + 8];
            const f32x4 w3 = *(const f32x4*)&Wh_s[k][c0 + 12];
            #pragma unroll
            for (int e = 0; e < 4; e++) {
                ha[e]      += xv * w0[e];
                ha[4 + e]  += xv * w1[e];
                ha[8 + e]  += xv * w2[e];
                ha[12 + e] += xv * w3[e];
            }
        }
        #pragma unroll
        for (int i = 0; i < 4; i++) {
            f32x4 t; t[0] = ha[4*i]; t[1] = ha[4*i+1]; t[2] = ha[4*i+2]; t[3] = ha[4*i+3];
            *(f32x4*)&h_s[w][lane16][c0 + 4 * i] = t;
        }
    }
    __syncthreads();

    #pragma unroll
    for (int cb = 0; cb < 4; cb++) {
        union { s16x4 v; uint2 u; } hp;
        #pragma unroll
        for (int e = 0; e < 4; e++)
            hp.v[e] = f2bf(h_s[w][g4 * 4 + e][cb * 16 + lane16]);
        kv[((size_t)(b * NKT + ktb) * 5 + 1 + cb) * 64 + L] = hp.u;
    }
}

// ---------------------------------------------------------------------------
// Kernel 2: flash attention, key-split. Block = (b, qblk of 4 qtiles, split).
// 4 waves share LDS-staged keys; each wave owns one 16-query tile.
// Partial (m, l, O-bf16) per (b,qt,split) to workspace.
// ---------------------------------------------------------------------------
template<int SPLITT>
__global__ __launch_bounds__(256, 6) void attn_kernel(
    const uint8_t* __restrict__ ws_in,
    uint8_t* __restrict__ ws_out)
{
    constexpr int TPS = NKT / SPLITT;
    constexpr int NST = TPS / STAGE_KT;
    __shared__ uint2 kvs[STAGE_KT * 5 * 64];   // 12,800 B

    const int tid = threadIdx.x;
    const int L = tid & 63, w = tid >> 6;
    const int lane16 = L & 15, g4 = L >> 4;

    const int bid = blockIdx.x;                // NB*125*SPLITT blocks
    const int qblk = bid % 125;
    const int bs = bid / 125;
    const int b = bs / SPLITT, s = bs % SPLITT;
    const int qt = qblk * 4 + w;

    const uint2* kv = (const uint2*)ws_in;
    const uint2* gB = (const uint2*)(ws_in + GB_OFF);
    float* part_ml = (float*)(ws_out + PML_OFF);
    uint2* part_O  = (uint2*)(ws_out + po_off(SPLITT));

    s16x4 bg;
    { union { uint2 u; s16x4 v; } t; t.u = gB[(size_t)(b * NKT + qt) * 64 + L]; bg = t.v; }

    float m_run = -1e30f, l_part = 0.f;
    f32x4 o0 = {0, 0, 0, 0}, o1 = {0, 0, 0, 0}, o2 = {0, 0, 0, 0}, o3 = {0, 0, 0, 0};

    const int kt0 = s * TPS;

    for (int st = 0; st < NST; st++) {
        __syncthreads();
        const uint2* src = kv + (size_t)(b * NKT + kt0 + st * STAGE_KT) * 5 * 64;
        {
            uint2 tmp[6];
            #pragma unroll
            for (int i = 0; i < 6; i++) tmp[i] = src[tid + i * 256];
            uint2 tail;
            if (tid < 64) tail = src[1536 + tid];
            #pragma unroll
            for (int i = 0; i < 6; i++) kvs[tid + i * 256] = tmp[i];
            if (tid < 64) kvs[1536 + tid] = tail;
        }
        __syncthreads();

        #pragma unroll
        for (int ktl = 0; ktl < STAGE_KT; ktl++) {
            const uint2* base = &kvs[ktl * 5 * 64];
            s16x4 af;
            { union { uint2 u; s16x4 v; } t; t.u = base[L]; af = t.v; }
            f32x4 z = {0, 0, 0, 0};
            f32x4 sv = __builtin_amdgcn_mfma_f32_16x16x16bf16_1k(af, bg, z, 0, 0, 0);

            float mt = fmaxf(fmaxf(sv[0], sv[1]), fmaxf(sv[2], sv[3]));
            if (__any(mt > m_run + RESCALE_THR)) {
                float mc = fmaxf(mt, __shfl_xor(mt, 16));
                mc = fmaxf(mc, __shfl_xor(mc, 32));
                float mnew = fmaxf(m_run, mc);
                float sc = exp2f(m_run - mnew);
                l_part *= sc;
                float s0 = __shfl(sc, g4 * 4 + 0);
                float s1 = __shfl(sc, g4 * 4 + 1);
                float s2 = __shfl(sc, g4 * 4 + 2);
                float s3 = __shfl(sc, g4 * 4 + 3);
                o0[0] *= s0; o0[1] *= s1; o0[2] *= s2; o0[3] *= s3;
                o1[0] *= s0; o1[1] *= s1; o1[2] *= s2; o1[3] *= s3;
                o2[0] *= s0; o2[1] *= s1; o2[2] *= s2; o2[3] *= s3;
                o3[0] *= s0; o3[1] *= s1; o3[2] *= s2; o3[3] *= s3;
                m_run = mnew;
            }

            float p0 = exp2f(sv[0] - m_run);
            float p1 = exp2f(sv[1] - m_run);
            float p2 = exp2f(sv[2] - m_run);
            float p3 = exp2f(sv[3] - m_run);
            l_part += (p0 + p1) + (p2 + p3);

            union { s16x4 v; uint2 u; } pp;
            pp.v[0] = f2bf_fast(p0); pp.v[1] = f2bf_fast(p1);
            pp.v[2] = f2bf_fast(p2); pp.v[3] = f2bf_fast(p3);

            s16x4 h0, h1, h2, h3;
            { union { uint2 u; s16x4 v; } t; t.u = base[ 64 + L]; h0 = t.v; }
            { union { uint2 u; s16x4 v; } t; t.u = base[128 + L]; h1 = t.v; }
            { union { uint2 u; s16x4 v; } t; t.u = base[192 + L]; h2 = t.v; }
            { union { uint2 u; s16x4 v; } t; t.u = base[256 + L]; h3 = t.v; }

            o0 = __builtin_amdgcn_mfma_f32_16x16x16bf16_1k(pp.v, h0, o0, 0, 0, 0);
            o1 = __builtin_amdgcn_mfma_f32_16x16x16bf16_1k(pp.v, h1, o1, 0, 0, 0);
            o2 = __builtin_amdgcn_mfma_f32_16x16x16bf16_1k(pp.v, h2, o2, 0, 0, 0);
            o3 = __builtin_amdgcn_mfma_f32_16x16x16bf16_1k(pp.v, h3, o3, 0, 0, 0);
        }
    }

    // ---- epilogue: reduce l across lane groups, store bf16 partials ----
    float lsum = l_part;
    lsum += __shfl_xor(lsum, 16);
    lsum += __shfl_xor(lsum, 32);

    const size_t pslot = (size_t)(b * NKT + qt) * SPLITT + s;
    if (g4 == 0) {
        part_ml[pslot * 32 + lane16] = m_run;
        part_ml[pslot * 32 + 16 + lane16] = lsum;
    }
    uint2* obase = part_O + pslot * 256;     // [row16][j16] uint2 = ch {j, j+16, j+32, j+48}
    #pragma unroll
    for (int r = 0; r < 4; r++) {
        const int row = g4 * 4 + r;
        union { s16x4 v; uint2 u; } ou;
        ou.v[0] = f2bf(o0[r]); ou.v[1] = f2bf(o1[r]);
        ou.v[2] = f2bf(o2[r]); ou.v[3] = f2bf(o3[r]);
        obase[row * 16 + lane16] = ou.u;
    }
}

// ---------------------------------------------------------------------------
// Kernel 3: combine splits + gamma/residual. Thread = (row, j); handles the
// 4 channels {j, j+16, j+32, j+48} packed in one uint2 per split.
// ---------------------------------------------------------------------------
template<int SPLITT>
__global__ __launch_bounds__(256) void combine_kernel(
    const float* __restrict__ x,
    const float* __restrict__ gammap,
    const uint8_t* __restrict__ ws,
    float* __restrict__ out)
{
    const int idx = blockIdx.x * 256 + threadIdx.x;   // 0 .. 255,999
    const int j = idx & 15;
    const int row_g = idx >> 4;                        // 0..15999
    const int b = row_g / NN;
    const int row = row_g - b * NN;
    const int qt = row >> 4, q = row & 15;

    const float* part_ml = (const float*)(ws + PML_OFF);
    const uint2* part_O  = (const uint2*)(ws + po_off(SPLITT));
    const size_t pbase = (size_t)(b * NKT + qt) * SPLITT;

    float m_s[SPLITT];
    float M = -1e30f;
    #pragma unroll
    for (int s = 0; s < SPLITT; s++) {
        m_s[s] = part_ml[(pbase + s) * 32 + q];
        M = fmaxf(M, m_s[s]);
    }
    float Lsum = 0.f, O0 = 0.f, O1 = 0.f, O2 = 0.f, O3 = 0.f;
    #pragma unroll
    for (int s = 0; s < SPLITT; s++) {
        float wgt = exp2f(m_s[s] - M);
        Lsum += part_ml[(pbase + s) * 32 + 16 + q] * wgt;
        uint2 u = part_O[(pbase + s) * 256 + q * 16 + j];
        O0 += wgt * __uint_as_float(u.x << 16);
        O1 += wgt * __uint_as_float(u.x & 0xffff0000u);
        O2 += wgt * __uint_as_float(u.y << 16);
        O3 += wgt * __uint_as_float(u.y & 0xffff0000u);
    }
    const float inv = gammap[0] / Lsum;
    const size_t base = (size_t)row_g * 64 + j;
    out[base +  0] = O0 * inv + x[base +  0];
    out[base + 16] = O1 * inv + x[base + 16];
    out[base + 32] = O2 * inv + x[base + 32];
    out[base + 48] = O3 * inv + x[base + 48];
}

extern "C" void kernel_launch(void* const* d_in, const int* in_sizes, int n_in,
                              void* d_out, int out_size, void* d_ws, size_t ws_size,
                              hipStream_t stream) {
    const float* x     = (const float*)d_in[0];
    const float* Wf    = (const float*)d_in[1];
    const float* Wg    = (const float*)d_in[2];
    const float* Wh    = (const float*)d_in[3];
    const float* gamma = (const float*)d_in[4];
    float* out = (float*)d_out;
    uint8_t* ws = (uint8_t*)d_ws;

    proj_kernel<<<250, 256, 0, stream>>>(x, Wf, Wg, Wh, ws);

    const size_t need10 = po_off(10) + po_bytes(10);   // 24,832,000 B
    if (ws_size >= need10) {
        attn_kernel<10><<<NB * 125 * 10, 256, 0, stream>>>(ws, ws);
        combine_kernel<10><<<(NB * NN * 16) / 256, 256, 0, stream>>>(x, gamma, ws, out);
    } else {
        attn_kernel<5><<<NB * 125 * 5, 256, 0, stream>>>(ws, ws);
        combine_kernel<5><<<(NB * NN * 16) / 256, 256, 0, stream>>>(x, gamma, ws, out);
    }
}

// Round 5
// 76.384 us; speedup vs baseline: 2.2770x; 1.0029x over previous
//
#include <hip/hip_runtime.h>
#include <stdint.h>
#include <stddef.h>

#define NB 2
#define NN 8000
#define NC 64
#define NKT 500          // N/16 key tiles
#define STAGE_KT 5       // key tiles per LDS stage buffer (12.8 KB each, x2)
#define RESCALE_THR 8.0f // log2 domain
#define LOG2E 1.44269504f

// ---- workspace layout (bytes) ----
#define KV_BYTES  ((size_t)NB * NKT * 5 * 64 * 8)   // 2,560,000: f frag + 4 h frags (bf16)
#define GB_OFF    KV_BYTES                          // g frags
#define GB_BYTES  ((size_t)NB * NKT * 64 * 8)       // 512,000
#define PML_OFF   (GB_OFF + GB_BYTES)               // m[16], l[16] per (b,qt,split)

__host__ __device__ constexpr size_t pml_bytes(int s) { return (size_t)NB * NKT * s * 32 * 4; }
__host__ __device__ constexpr size_t po_off(int s)    { return PML_OFF + pml_bytes(s); }
// partial O: per (b,qt,split) 16 rows x 16 j x uint2 (4 bf16) = 2048 B
__host__ __device__ constexpr size_t po_bytes(int s)  { return (size_t)NB * NKT * s * 2048; }

typedef float f32x4 __attribute__((ext_vector_type(4)));
typedef short s16x4 __attribute__((ext_vector_type(4)));

__device__ inline short f2bf(float f) {                // RNE to bf16 (bitwise, proven)
    union { float f; uint32_t u; } v; v.f = f;
    uint32_t u = v.u + 0x7FFFu + ((v.u >> 16) & 1u);
    return (short)(u >> 16);
}
__device__ inline short f2bf_fast(float f) {           // round-half-up in magnitude
    union { float f; uint32_t u; } v; v.f = f;
    return (short)((v.u + 0x8000u) >> 16);
}

// ---------------------------------------------------------------------------
// Kernel 1: projections f = x(Wf*log2e), g = xWg, h = xWh, in MFMA fragment
// order (bf16). kv[b][kt][sub][lane]: sub0 = f A-frag (K padded 8->16 zeros),
// sub1..4 = h B-frags per column block. gB[b][qt][lane] = g B-frag.
// mfma_f32_16x16x16_bf16 maps: A row=lane&15,k=(lane>>4)*4+e ; B col=lane&15,
// k=(lane>>4)*4+e ; C/D col=lane&15, row=(lane>>4)*4+reg.
// ---------------------------------------------------------------------------
__global__ __launch_bounds__(256) void proj_kernel(
    const float* __restrict__ x,
    const float* __restrict__ Wf,
    const float* __restrict__ Wg,
    const float* __restrict__ Wh,
    uint8_t* __restrict__ ws)
{
    __shared__ float Wh_s[64][68];
    __shared__ float Wf_s[64][8];
    __shared__ float Wg_s[64][8];
    __shared__ float x_s[4][16][68];
    __shared__ float h_s[4][16][68];

    const int tid = threadIdx.x;
    const int L = tid & 63, w = tid >> 6;
    const int lane16 = L & 15, g4 = L >> 4;

    for (int i = tid; i < 64 * 64; i += 256) Wh_s[i >> 6][i & 63] = Wh[i];
    for (int i = tid; i < 64 * 8; i += 256) {
        Wf_s[i >> 3][i & 7] = Wf[i] * LOG2E;   // scores in log2 domain
        Wg_s[i >> 3][i & 7] = Wg[i];
    }

    const int ktg = blockIdx.x * 4 + w;      // 0..999
    const int b = ktg / NKT, ktb = ktg % NKT;
    const float* xsrc = x + ((size_t)b * NN + (size_t)ktb * 16) * NC;

    #pragma unroll
    for (int i = 0; i < 4; i++) {
        int F = i * 256 + L * 4;
        f32x4 v = *(const f32x4*)(xsrc + F);
        *(f32x4*)&x_s[w][F >> 6][F & 63] = v;
    }
    __syncthreads();

    uint2* kv = (uint2*)ws;
    uint2* gB = (uint2*)(ws + GB_OFF);

    {
        float fa0 = 0, fa1 = 0, fa2 = 0, fa3 = 0;
        float ga0 = 0, ga1 = 0, ga2 = 0, ga3 = 0;
        const int d0 = (g4 & 1) * 4;
        #pragma unroll 4
        for (int k = 0; k < 64; k++) {
            float xv = x_s[w][lane16][k];
            fa0 += xv * Wf_s[k][d0 + 0]; fa1 += xv * Wf_s[k][d0 + 1];
            fa2 += xv * Wf_s[k][d0 + 2]; fa3 += xv * Wf_s[k][d0 + 3];
            ga0 += xv * Wg_s[k][d0 + 0]; ga1 += xv * Wg_s[k][d0 + 1];
            ga2 += xv * Wg_s[k][d0 + 2]; ga3 += xv * Wg_s[k][d0 + 3];
        }
        const bool valid = (g4 < 2);
        union { s16x4 v; uint2 u; } fp, gp;
        fp.v[0] = valid ? f2bf(fa0) : (short)0;
        fp.v[1] = valid ? f2bf(fa1) : (short)0;
        fp.v[2] = valid ? f2bf(fa2) : (short)0;
        fp.v[3] = valid ? f2bf(fa3) : (short)0;
        gp.v[0] = valid ? f2bf(ga0) : (short)0;
        gp.v[1] = valid ? f2bf(ga1) : (short)0;
        gp.v[2] = valid ? f2bf(ga2) : (short)0;
        gp.v[3] = valid ? f2bf(ga3) : (short)0;
        kv[((size_t)(b * NKT + ktb) * 5 + 0) * 64 + L] = fp.u;
        gB[(size_t)(b * NKT + ktb) * 64 + L] = gp.u;
    }

    {
        float ha[16];
        #pragma unroll
        for (int i = 0; i < 16; i++) ha[i] = 0.f;
        const int c0 = g4 * 16;
        for (int k = 0; k < 64; k++) {
            float xv = x_s[w][lane16][k];
            const f32x4 w0 = *(const f32x4*)&Wh_s[k][c0 + 0];
            const f32x4 w1 = *(const f32x4*)&Wh_s[k][c0 + 4];
            const f32x4 w2 = *(const f32x4*)&Wh_s[k][c0 + 8];
            const f32x4 w3 = *(const f32x4*)&Wh_s[k][c0 + 12];
            #pragma unroll
            for (int e = 0; e < 4; e++) {
                ha[e]      += xv * w0[e];
                ha[4 + e]  += xv * w1[e];
                ha[8 + e]  += xv * w2[e];
                ha[12 + e] += xv * w3[e];
            }
        }
        #pragma unroll
        for (int i = 0; i < 4; i++) {
            f32x4 t; t[0] = ha[4*i]; t[1] = ha[4*i+1]; t[2] = ha[4*i+2]; t[3] = ha[4*i+3];
            *(f32x4*)&h_s[w][lane16][c0 + 4 * i] = t;
        }
    }
    __syncthreads();

    #pragma unroll
    for (int cb = 0; cb < 4; cb++) {
        union { s16x4 v; uint2 u; } hp;
        #pragma unroll
        for (int e = 0; e < 4; e++)
            hp.v[e] = f2bf(h_s[w][g4 * 4 + e][cb * 16 + lane16]);
        kv[((size_t)(b * NKT + ktb) * 5 + 1 + cb) * 64 + L] = hp.u;
    }
}

// ---------------------------------------------------------------------------
// Kernel 2: flash attention, key-split, double-buffered T14 staging.
// Block = (b, qblk of 4 qtiles, split). 4 waves share LDS-staged keys; each
// wave owns one 16-query tile. Per stage: compute from buf[cur] while next
// stage's global loads (issued last stage) are in flight; drain + ds_write
// into buf[cur^1] after compute; ONE barrier per stage.
// ---------------------------------------------------------------------------
template<int SPLITT>
__global__ __launch_bounds__(256, 4) void attn_kernel(
    const uint8_t* __restrict__ ws_in,
    uint8_t* __restrict__ ws_out)
{
    constexpr int TPS = NKT / SPLITT;
    constexpr int NST = TPS / STAGE_KT;
    __shared__ uint2 kvs[2][STAGE_KT * 5 * 64];   // 2 x 12,800 B

    const int tid = threadIdx.x;
    const int L = tid & 63, w = tid >> 6;
    const int lane16 = L & 15, g4 = L >> 4;

    const int bid = blockIdx.x;                // NB*125*SPLITT blocks
    const int qblk = bid % 125;
    const int bs = bid / 125;
    const int b = bs / SPLITT, s = bs % SPLITT;
    const int qt = qblk * 4 + w;

    const uint2* kv = (const uint2*)ws_in;
    const uint2* gB = (const uint2*)(ws_in + GB_OFF);
    float* part_ml = (float*)(ws_out + PML_OFF);
    uint2* part_O  = (uint2*)(ws_out + po_off(SPLITT));

    s16x4 bg;
    { union { uint2 u; s16x4 v; } t; t.u = gB[(size_t)(b * NKT + qt) * 64 + L]; bg = t.v; }

    float m_run = -1e30f, l_part = 0.f;
    f32x4 o0 = {0, 0, 0, 0}, o1 = {0, 0, 0, 0}, o2 = {0, 0, 0, 0}, o3 = {0, 0, 0, 0};

    const int kt0 = s * TPS;
    const uint2* stage_base = kv + (size_t)(b * NKT + kt0) * 5 * 64;

    uint2 tmp[6];        // in-flight next-stage data (T14 registers)
    uint2 tail;

    // ---- prologue: fill buf0 (stage 0), start loads for stage 1 ----
    {
        const uint2* src = stage_base;
        #pragma unroll
        for (int i = 0; i < 6; i++) tmp[i] = src[tid + i * 256];
        if (tid < 64) tail = src[1536 + tid];
        #pragma unroll
        for (int i = 0; i < 6; i++) kvs[0][tid + i * 256] = tmp[i];
        if (tid < 64) kvs[0][1536 + tid] = tail;
        const uint2* src1 = stage_base + 1600;
        #pragma unroll
        for (int i = 0; i < 6; i++) tmp[i] = src1[tid + i * 256];
        if (tid < 64) tail = src1[1536 + tid];
    }
    __syncthreads();

    for (int st = 0; st < NST; st++) {
        const int cur = st & 1;

        #pragma unroll
        for (int ktl = 0; ktl < STAGE_KT; ktl++) {
            const uint2* base = &kvs[cur][ktl * 5 * 64];
            s16x4 af;
            { union { uint2 u; s16x4 v; } t; t.u = base[L]; af = t.v; }
            f32x4 z = {0, 0, 0, 0};
            f32x4 sv = __builtin_amdgcn_mfma_f32_16x16x16bf16_1k(af, bg, z, 0, 0, 0);

            float mt = fmaxf(fmaxf(sv[0], sv[1]), fmaxf(sv[2], sv[3]));
            if (__any(mt > m_run + RESCALE_THR)) {
                float mc = fmaxf(mt, __shfl_xor(mt, 16));
                mc = fmaxf(mc, __shfl_xor(mc, 32));
                float mnew = fmaxf(m_run, mc);
                float sc = exp2f(m_run - mnew);
                l_part *= sc;
                float s0 = __shfl(sc, g4 * 4 + 0);
                float s1 = __shfl(sc, g4 * 4 + 1);
                float s2 = __shfl(sc, g4 * 4 + 2);
                float s3 = __shfl(sc, g4 * 4 + 3);
                o0[0] *= s0; o0[1] *= s1; o0[2] *= s2; o0[3] *= s3;
                o1[0] *= s0; o1[1] *= s1; o1[2] *= s2; o1[3] *= s3;
                o2[0] *= s0; o2[1] *= s1; o2[2] *= s2; o2[3] *= s3;
                o3[0] *= s0; o3[1] *= s1; o3[2] *= s2; o3[3] *= s3;
                m_run = mnew;
            }

            float p0 = exp2f(sv[0] - m_run);
            float p1 = exp2f(sv[1] - m_run);
            float p2 = exp2f(sv[2] - m_run);
            float p3 = exp2f(sv[3] - m_run);
            l_part += (p0 + p1) + (p2 + p3);

            union { s16x4 v; uint2 u; } pp;
            pp.v[0] = f2bf_fast(p0); pp.v[1] = f2bf_fast(p1);
            pp.v[2] = f2bf_fast(p2); pp.v[3] = f2bf_fast(p3);

            s16x4 h0, h1, h2, h3;
            { union { uint2 u; s16x4 v; } t; t.u = base[ 64 + L]; h0 = t.v; }
            { union { uint2 u; s16x4 v; } t; t.u = base[128 + L]; h1 = t.v; }
            { union { uint2 u; s16x4 v; } t; t.u = base[192 + L]; h2 = t.v; }
            { union { uint2 u; s16x4 v; } t; t.u = base[256 + L]; h3 = t.v; }

            o0 = __builtin_amdgcn_mfma_f32_16x16x16bf16_1k(pp.v, h0, o0, 0, 0, 0);
            o1 = __builtin_amdgcn_mfma_f32_16x16x16bf16_1k(pp.v, h1, o1, 0, 0, 0);
            o2 = __builtin_amdgcn_mfma_f32_16x16x16bf16_1k(pp.v, h2, o2, 0, 0, 0);
            o3 = __builtin_amdgcn_mfma_f32_16x16x16bf16_1k(pp.v, h3, o3, 0, 0, 0);
        }

        // ---- T14 drain + refill: write stage st+1 into idle buffer ----
        if (st + 1 < NST) {
            #pragma unroll
            for (int i = 0; i < 6; i++) kvs[cur ^ 1][tid + i * 256] = tmp[i];
            if (tid < 64) kvs[cur ^ 1][1536 + tid] = tail;
            if (st + 2 < NST) {
                const uint2* srcn = stage_base + (size_t)(st + 2) * 1600;
                #pragma unroll
                for (int i = 0; i < 6; i++) tmp[i] = srcn[tid + i * 256];
                if (tid < 64) tail = srcn[1536 + tid];
            }
        }
        __syncthreads();
    }

    // ---- epilogue: reduce l across lane groups, store bf16 partials ----
    float lsum = l_part;
    lsum += __shfl_xor(lsum, 16);
    lsum += __shfl_xor(lsum, 32);

    const size_t pslot = (size_t)(b * NKT + qt) * SPLITT + s;
    if (g4 == 0) {
        part_ml[pslot * 32 + lane16] = m_run;
        part_ml[pslot * 32 + 16 + lane16] = lsum;
    }
    uint2* obase = part_O + pslot * 256;     // [row16][j16] uint2 = ch {j, j+16, j+32, j+48}
    #pragma unroll
    for (int r = 0; r < 4; r++) {
        const int row = g4 * 4 + r;
        union { s16x4 v; uint2 u; } ou;
        ou.v[0] = f2bf(o0[r]); ou.v[1] = f2bf(o1[r]);
        ou.v[2] = f2bf(o2[r]); ou.v[3] = f2bf(o3[r]);
        obase[row * 16 + lane16] = ou.u;
    }
}

// ---------------------------------------------------------------------------
// Kernel 3: combine splits + gamma/residual. Thread = (row, j); handles the
// 4 channels {j, j+16, j+32, j+48} packed in one uint2 per split.
// ---------------------------------------------------------------------------
template<int SPLITT>
__global__ __launch_bounds__(256) void combine_kernel(
    const float* __restrict__ x,
    const float* __restrict__ gammap,
    const uint8_t* __restrict__ ws,
    float* __restrict__ out)
{
    const int idx = blockIdx.x * 256 + threadIdx.x;   // 0 .. 255,999
    const int j = idx & 15;
    const int row_g = idx >> 4;                        // 0..15999
    const int b = row_g / NN;
    const int row = row_g - b * NN;
    const int qt = row >> 4, q = row & 15;

    const float* part_ml = (const float*)(ws + PML_OFF);
    const uint2* part_O  = (const uint2*)(ws + po_off(SPLITT));
    const size_t pbase = (size_t)(b * NKT + qt) * SPLITT;

    float m_s[SPLITT];
    float M = -1e30f;
    #pragma unroll
    for (int s = 0; s < SPLITT; s++) {
        m_s[s] = part_ml[(pbase + s) * 32 + q];
        M = fmaxf(M, m_s[s]);
    }
    float Lsum = 0.f, O0 = 0.f, O1 = 0.f, O2 = 0.f, O3 = 0.f;
    #pragma unroll
    for (int s = 0; s < SPLITT; s++) {
        float wgt = exp2f(m_s[s] - M);
        Lsum += part_ml[(pbase + s) * 32 + 16 + q] * wgt;
        uint2 u = part_O[(pbase + s) * 256 + q * 16 + j];
        O0 += wgt * __uint_as_float(u.x << 16);
        O1 += wgt * __uint_as_float(u.x & 0xffff0000u);
        O2 += wgt * __uint_as_float(u.y << 16);
        O3 += wgt * __uint_as_float(u.y & 0xffff0000u);
    }
    const float inv = gammap[0] / Lsum;
    const size_t base = (size_t)row_g * 64 + j;
    out[base +  0] = O0 * inv + x[base +  0];
    out[base + 16] = O1 * inv + x[base + 16];
    out[base + 32] = O2 * inv + x[base + 32];
    out[base + 48] = O3 * inv + x[base + 48];
}

extern "C" void kernel_launch(void* const* d_in, const int* in_sizes, int n_in,
                              void* d_out, int out_size, void* d_ws, size_t ws_size,
                              hipStream_t stream) {
    const float* x     = (const float*)d_in[0];
    const float* Wf    = (const float*)d_in[1];
    const float* Wg    = (const float*)d_in[2];
    const float* Wh    = (const float*)d_in[3];
    const float* gamma = (const float*)d_in[4];
    float* out = (float*)d_out;
    uint8_t* ws = (uint8_t*)d_ws;

    proj_kernel<<<250, 256, 0, stream>>>(x, Wf, Wg, Wh, ws);

    const size_t need10 = po_off(10) + po_bytes(10);   // 24,832,000 B
    if (ws_size >= need10) {
        attn_kernel<10><<<NB * 125 * 10, 256, 0, stream>>>(ws, ws);
        combine_kernel<10><<<(NB * NN * 16) / 256, 256, 0, stream>>>(x, gamma, ws, out);
    } else {
        attn_kernel<5><<<NB * 125 * 5, 256, 0, stream>>>(ws, ws);
        combine_kernel<5><<<(NB * NN * 16) / 256, 256, 0, stream>>>(x, gamma, ws, out);
    }
}